// Round 6
// baseline (188.270 us; speedup 1.0000x reference)
//
#include <hip/hip_runtime.h>
#include <math.h>

#define NN 4096
#define DD 256
#define KK 2048
#define NW 64        // u64 words per bitmask row
#define SK 4         // K chunks for MFMA staging
#define KC (NN / SK) // 1024 K per chunk
#define KW (KC / 32) // 32 u32 words per row-chunk

typedef float f32x4  __attribute__((ext_vector_type(4)));
typedef short bf16x8 __attribute__((ext_vector_type(8)));

// Build sorted column list for bitmask row r into LDS `cols` (one wave, lane l).
__device__ __forceinline__ int build_list(const unsigned long long* __restrict__ B, int r,
                                          int l, int* cols, int cap) {
    unsigned long long word = B[(size_t)r * NW + l];
    int pc = __popcll(word);
    int off = pc;
    for (int d = 1; d < 64; d <<= 1) {
        int n = __shfl_up(off, d);
        if (l >= d) off += n;
    }
    int total = __shfl(off, 63);
    int base = off - pc;
    while (word) {
        int b = (int)__ffsll(word) - 1;
        word &= word - 1;
        if (base < cap) cols[base] = l * 64 + b;
        ++base;
    }
    return total;
}

// ---------------- D1: column stats partials (blocks 0..63) + g bitmask (blocks 64..4159) ------
__global__ void k_pre(const float* __restrict__ h, const float* __restrict__ g,
                      double* __restrict__ psum, double* __restrict__ psq,
                      unsigned long long* __restrict__ B) {
    int blk = blockIdx.x;
    int t = threadIdx.x;   // 256
    if (blk < 64) {
        int d = t;
        int r0 = blk * 64;
        double s0=0,s1=0,s2=0,s3=0,q0=0,q1=0,q2=0,q3=0;
        for (int k = 0; k < 64; k += 4) {
            double x0 = (double)h[(size_t)(r0+k+0) * DD + d];
            double x1 = (double)h[(size_t)(r0+k+1) * DD + d];
            double x2 = (double)h[(size_t)(r0+k+2) * DD + d];
            double x3 = (double)h[(size_t)(r0+k+3) * DD + d];
            s0 += x0; q0 += x0*x0;
            s1 += x1; q1 += x1*x1;
            s2 += x2; q2 += x2*x2;
            s3 += x3; q3 += x3*x3;
        }
        psum[blk * DD + d] = (s0+s1)+(s2+s3);
        psq [blk * DD + d] = (q0+q1)+(q2+q3);
    } else {
        int i = blk - 64;
        int q = t >> 6, l = t & 63;
        const float* gr = g + (size_t)i * NN;
        unsigned long long word = 0ull;
        int lw = l & 15;
        #pragma unroll
        for (int wi = 0; wi < 16; ++wi) {
            float v = gr[(q * 16 + wi) * 64 + l];
            unsigned long long m = __ballot(v != 0.0f);
            if (wi == lw) word = m;   // lane l keeps word q*16 + (l&15)
        }
        if (l < 16) B[(size_t)i * NW + q * 16 + l] = word;
    }
}

// ---------------- D2: stats final: 1 block x 1024 ----------------
__global__ void k_stats_final(const double* __restrict__ psum, const double* __restrict__ psq,
                              double* __restrict__ mu, double* __restrict__ rstd) {
    __shared__ double rs[4][DD];
    __shared__ double rq[4][DD];
    int t = threadIdx.x;
    int d = t & (DD - 1);
    int q = t >> 8;
    double s0=0,s1=0,q0=0,q1=0;
    int b0 = q * 16;
    for (int k = 0; k < 16; k += 2) {
        s0 += psum[(b0+k)   * DD + d];
        s1 += psum[(b0+k+1) * DD + d];
        q0 += psq [(b0+k)   * DD + d];
        q1 += psq [(b0+k+1) * DD + d];
    }
    rs[q][d] = s0 + s1;
    rq[q][d] = q0 + q1;
    __syncthreads();
    if (q == 0) {
        double S  = (rs[0][d]+rs[1][d]) + (rs[2][d]+rs[3][d]);
        double Q  = (rq[0][d]+rq[1][d]) + (rq[2][d]+rq[3][d]);
        double m  = S / (double)NN;
        double var = Q / (double)NN - m * m;
        mu[d]   = m;
        rstd[d] = 1.0 / sqrt(var + 1e-5);
    }
}

// ---- D3: main: wave per row, ONE list build feeding BOTH agg+norm+zpf AND twohop OR ----------
__global__ void k_main(const float* __restrict__ h, const double* __restrict__ mu,
                       const double* __restrict__ rstd, const float* __restrict__ gamma,
                       const float* __restrict__ beta, const unsigned long long* __restrict__ Bm,
                       const float* __restrict__ w, const float* __restrict__ bp,
                       float* __restrict__ hn, double* __restrict__ zpf,
                       unsigned long long* __restrict__ T, double* __restrict__ Z1,
                       double* __restrict__ Z3, int* __restrict__ degi) {
    __shared__ int cols[4][136];
    int blk = blockIdx.x;
    int t = threadIdx.x;
    int wv = t >> 6, l = t & 63;
    int r = blk * 4 + wv;
    int cnt = build_list(Bm, r, l, cols[wv], 128);
    if (cnt > 128) cnt = 128;
    const float4* h4 = (const float4*)h;
    double s0=0,s1=0,s2=0,s3=0,u0=0,u1=0,u2=0,u3=0;
    unsigned long long a0 = 0ull, a1 = 0ull;
    int j = 0;
    for (; j + 1 < cnt; j += 2) {
        int c0 = cols[wv][j], c1 = cols[wv][j + 1];
        float4 v0 = h4[(size_t)c0 * 64 + l];
        float4 v1 = h4[(size_t)c1 * 64 + l];
        a0 |= Bm[(size_t)c0 * NW + l];
        a1 |= Bm[(size_t)c1 * NW + l];
        s0 += (double)v0.x; s1 += (double)v0.y; s2 += (double)v0.z; s3 += (double)v0.w;
        u0 += (double)v1.x; u1 += (double)v1.y; u2 += (double)v1.z; u3 += (double)v1.w;
    }
    if (j < cnt) {
        int c0 = cols[wv][j];
        float4 v0 = h4[(size_t)c0 * 64 + l];
        a0 |= Bm[(size_t)c0 * NW + l];
        s0 += (double)v0.x; s1 += (double)v0.y; s2 += (double)v0.z; s3 += (double)v0.w;
    }
    T[(size_t)r * NW + l] = a0 | a1;
    s0 += u0; s1 += u1; s2 += u2; s3 += u3;
    const double2* mu2 = (const double2*)mu;
    const double2* rs2 = (const double2*)rstd;
    const float4*  ga4 = (const float4*)gamma;
    const float4*  be4 = (const float4*)beta;
    const float4*  w4  = (const float4*)w;
    double2 mA = mu2[2*l], mB = mu2[2*l+1];
    double2 rA = rs2[2*l], rB = rs2[2*l+1];
    float4 ga = ga4[l], be = be4[l], wl = w4[l];
    double inv = 1.0 / (double)cnt;
    double g0 = (s0 * inv - mA.x) * rA.x * (double)ga.x + (double)be.x;
    double g1 = (s1 * inv - mA.y) * rA.y * (double)ga.y + (double)be.y;
    double g2 = (s2 * inv - mB.x) * rB.x * (double)ga.z + (double)be.z;
    double g3 = (s3 * inv - mB.y) * rB.y * (double)ga.w + (double)be.w;
    float4 hv = h4[(size_t)r * 64 + l];
    double h0 = ((double)hv.x - mA.x) * rA.x * (double)ga.x + (double)be.x;
    double h1 = ((double)hv.y - mA.y) * rA.y * (double)ga.y + (double)be.y;
    double h2 = ((double)hv.z - mB.x) * rB.x * (double)ga.z + (double)be.z;
    double h3 = ((double)hv.w - mB.y) * rB.y * (double)ga.w + (double)be.w;
    float4 o = { (float)h0, (float)h1, (float)h2, (float)h3 };
    ((float4*)hn)[(size_t)r * 64 + l] = o;
    double z1p = (fabs(h0 - g0) + fabs(h1 - g1)) + (fabs(h2 - g2) + fabs(h3 - g3));
    double z3p = (g0 * (double)wl.x + g1 * (double)wl.y)
               + (g2 * (double)wl.z + g3 * (double)wl.w);
    double zfp = (h0 * (double)wl.x + h1 * (double)wl.y)
               + (h2 * (double)wl.z + h3 * (double)wl.w);
    for (int off = 32; off > 0; off >>= 1) {
        z1p += __shfl_down(z1p, off);
        z3p += __shfl_down(z3p, off);
        zfp += __shfl_down(zfp, off);
    }
    if (l == 0) {
        Z1[r] = z1p;
        Z3[r] = z3p + (double)bp[0];
        zpf[r] = zfp + (double)bp[0];
        degi[r] = cnt;
    }
}

// ---------------- D4: scores + keys: 16 blocks, redundant softmax stats (deterministic) -------
__global__ void k_scorekeys(const double* __restrict__ Z1, const double* __restrict__ Z3,
                            const double* __restrict__ zpf, const int* __restrict__ degi,
                            const float* __restrict__ sigma1, float* __restrict__ scores,
                            unsigned long long* __restrict__ keys) {
    __shared__ double red[256];
    int t = threadIdx.x;
    double mx = -1e300;
    for (int k = 0; k < 16; ++k) mx = fmax(mx, Z3[t + 256 * k]);
    red[t] = mx;
    __syncthreads();
    for (int s = 128; s > 0; s >>= 1) {
        if (t < s) red[t] = fmax(red[t], red[t + s]);
        __syncthreads();
    }
    double M = red[0];
    __syncthreads();
    double se = 0.0;
    for (int k = 0; k < 16; ++k) se += exp(Z3[t + 256 * k] - M);
    red[t] = se;
    __syncthreads();
    for (int s = 128; s > 0; s >>= 1) {
        if (t < s) red[t] += red[t + s];
        __syncthreads();
    }
    double sum = red[0];
    int i = blockIdx.x * 256 + t;
    double s1 = (double)sigma1[0];
    double pg = exp(Z3[i] - M) / sum;
    double pl = 1.0 / (1.0 + exp(-(Z1[i] + (double)degi[i])));
    double pt = 1.0 / (1.0 + exp(-(pl + pg)));
    double pf = 1.0 / (1.0 + exp(-zpf[i]));
    float sc = (float)(s1 * pt + (1.0 - s1) * pf);
    scores[i] = sc;
    unsigned int b2 = __float_as_uint(sc);
    unsigned int ka = (b2 & 0x80000000u) ? ~b2 : (b2 ^ 0x80000000u);  // ascending order key
    keys[i] = ((unsigned long long)(~ka) << 32) | (unsigned int)i;    // asc = desc score, asc idx
}

// ---- D5: rank-by-counting (blocks 0..255) || haT split/transpose (blocks 256..511) -----------
// haT_hi/haT_lo are [DD][NN] ushort (B^T layout for the MFMA B-fragment).
__global__ void k_sel(const unsigned long long* __restrict__ keys,
                      const float* __restrict__ scores, const float* __restrict__ hn,
                      unsigned short* __restrict__ haT_hi, unsigned short* __restrict__ haT_lo,
                      int* __restrict__ idx_int, float* __restrict__ out_idx) {
    __shared__ unsigned long long Kl[NN];   // 32 KB (rank blocks only)
    int bid = blockIdx.x;
    int t = threadIdx.x;   // 256
    int wv = t >> 6, l = t & 63;
    if (bid < 256) {
        for (int i = t; i < NN; i += 256) Kl[i] = keys[i];
        __syncthreads();
        int il = t >> 4, sub = t & 15;
        int i = bid * 16 + il;
        unsigned long long ki = Kl[i];
        int c0 = 0, c1 = 0, c2 = 0, c3 = 0;
        for (int jj = 0; jj < 256; jj += 4) {
            int jx = sub + (jj << 4);
            c0 += (Kl[jx]      < ki) ? 1 : 0;
            c1 += (Kl[jx + 16] < ki) ? 1 : 0;
            c2 += (Kl[jx + 32] < ki) ? 1 : 0;
            c3 += (Kl[jx + 48] < ki) ? 1 : 0;
        }
        int cnt = (c0 + c1) + (c2 + c3);
        for (int off = 8; off > 0; off >>= 1) cnt += __shfl_down(cnt, off, 16);
        if (sub == 0 && cnt < KK) {   // exact bijection: keys are unique
            idx_int[cnt] = i;
            out_idx[cnt] = (float)i;
        }
    } else {
        // haT: 256 blocks = 64 node-groups x 4 d-quarters; lane = node (coalesced stores)
        int bb = bid - 256;
        int ng = bb & 63, dq = bb >> 6;
        int node = ng * 64 + l;
        float sc = scores[node];
        const float* hr = hn + (size_t)node * DD;
        for (int d = dq * 64 + wv; d < (dq + 1) * 64; d += 4) {
            float x = hr[d] * sc;
            unsigned int xb = __float_as_uint(x);
            unsigned int hb = xb & 0xFFFF0000u;
            float lo = x - __uint_as_float(hb);
            unsigned int lb = __float_as_uint(lo);
            haT_hi[(size_t)d * NN + node] = (unsigned short)(hb >> 16);
            haT_lo[(size_t)d * NN + node] = (unsigned short)(lb >> 16);
        }
    }
}

// ---- D6: full-K MFMA new_h (blocks 0..255: 16 rs x 16 cb of 16 cols, 1 blk/CU) ||
//          g_new rows w/ in-block rowsum (blocks 256..2303) ----------------------------------
__global__ void k_out(const unsigned long long* __restrict__ T, const int* __restrict__ idx_int,
                      const unsigned short* __restrict__ haT_hi,
                      const unsigned short* __restrict__ haT_lo,
                      float* __restrict__ out_gnew, float* __restrict__ out_newh) {
    union Sm {
        struct { unsigned long long Tl[NW]; int redc[4]; } og;
        struct { int ids[128]; unsigned int Ab[128][KW + 1]; } nh;   // 17.4 KB
    };
    __shared__ Sm sm;
    int bid = blockIdx.x;
    int t = threadIdx.x;   // 256
    int wv = t >> 6, l = t & 63;
    if (bid < 256) {
        // ---- new_h: full K, 16 row-stripes x 16 col-blocks (16 d-cols each) ----
        int rs = bid >> 4, cb = bid & 15;
        if (t < 128) sm.nh.ids[t] = idx_int[rs * 128 + t];
        int lm = l & 15, lg = l >> 4;
        int row_base = wv * 32;             // wave tile: 32 rows (2 m-tiles) x 16 cols
        int col_base = cb * 16;
        f32x4 acc0 = (f32x4)0.0f, acc1 = (f32x4)0.0f;
        const unsigned short* ph = haT_hi + (size_t)(col_base + lm) * NN + lg * 8;
        const unsigned short* pl = haT_lo + (size_t)(col_base + lm) * NN + lg * 8;
        for (int kc = 0; kc < SK; ++kc) {
            __syncthreads();   // guards ids (kc=0) and Ab reuse (kc>0)
            for (int i = t; i < 128 * KW; i += 256) {
                int row = i >> 5, wd = i & (KW - 1);
                sm.nh.Ab[row][wd] =
                    ((const unsigned int*)(T + (size_t)sm.nh.ids[row] * NW))[kc * KW + wd];
            }
            __syncthreads();
            const unsigned short* phk = ph + kc * KC;
            const unsigned short* plk = pl + kc * KC;
            #pragma unroll 4
            for (int ks = 0; ks < KW; ++ks) {
                bf16x8 bh = *(const bf16x8*)(phk + ks * 32);
                bf16x8 bl = *(const bf16x8*)(plk + ks * 32);
                unsigned int bits0 = sm.nh.Ab[row_base + lm][ks];
                unsigned int bits1 = sm.nh.Ab[row_base + 16 + lm][ks];
                unsigned int b80 = (bits0 >> (8 * lg)) & 0xFFu;
                unsigned int b81 = (bits1 >> (8 * lg)) & 0xFFu;
                union { unsigned int u[4]; bf16x8 v; } a0, a1;
                a0.u[0] = ((b80 & 1u)        ? 0x3F80u : 0u) | ((b80 & 2u)   ? 0x3F800000u : 0u);
                a0.u[1] = (((b80 >> 2) & 1u) ? 0x3F80u : 0u) | ((b80 & 8u)   ? 0x3F800000u : 0u);
                a0.u[2] = (((b80 >> 4) & 1u) ? 0x3F80u : 0u) | ((b80 & 32u)  ? 0x3F800000u : 0u);
                a0.u[3] = (((b80 >> 6) & 1u) ? 0x3F80u : 0u) | ((b80 & 128u) ? 0x3F800000u : 0u);
                a1.u[0] = ((b81 & 1u)        ? 0x3F80u : 0u) | ((b81 & 2u)   ? 0x3F800000u : 0u);
                a1.u[1] = (((b81 >> 2) & 1u) ? 0x3F80u : 0u) | ((b81 & 8u)   ? 0x3F800000u : 0u);
                a1.u[2] = (((b81 >> 4) & 1u) ? 0x3F80u : 0u) | ((b81 & 32u)  ? 0x3F800000u : 0u);
                a1.u[3] = (((b81 >> 6) & 1u) ? 0x3F80u : 0u) | ((b81 & 128u) ? 0x3F800000u : 0u);
                acc0 = __builtin_amdgcn_mfma_f32_16x16x32_bf16(a0.v, bh, acc0, 0, 0, 0);
                acc1 = __builtin_amdgcn_mfma_f32_16x16x32_bf16(a1.v, bh, acc1, 0, 0, 0);
                acc0 = __builtin_amdgcn_mfma_f32_16x16x32_bf16(a0.v, bl, acc0, 0, 0, 0);
                acc1 = __builtin_amdgcn_mfma_f32_16x16x32_bf16(a1.v, bl, acc1, 0, 0, 0);
            }
        }
        // C/D layout (HW-verified): col = l&15, row = (l>>4)*4 + reg
        int col = col_base + lm;
        int row0 = rs * 128 + row_base + lg * 4;
        #pragma unroll
        for (int rr = 0; rr < 4; ++rr)
            out_newh[(size_t)(row0 + rr) * DD + col] = acc0[rr];
        #pragma unroll
        for (int rr = 0; rr < 4; ++rr)
            out_newh[(size_t)(row0 + 16 + rr) * DD + col] = acc1[rr];
    } else {
        // ---- g_new row: pass1 in-block count over selected cols, pass2 write ----
        int r = bid - 256;
        if (t < NW) sm.og.Tl[t] = T[(size_t)idx_int[r] * NW + t];
        __syncthreads();
        const int4* idx4 = (const int4*)idx_int;
        int cloc = 0;
        for (int c4 = t; c4 < KK / 4; c4 += 256) {
            int4 jc = idx4[c4];
            cloc += (int)((sm.og.Tl[jc.x >> 6] >> (jc.x & 63)) & 1ull)
                  + (int)((sm.og.Tl[jc.y >> 6] >> (jc.y & 63)) & 1ull)
                  + (int)((sm.og.Tl[jc.z >> 6] >> (jc.z & 63)) & 1ull)
                  + (int)((sm.og.Tl[jc.w >> 6] >> (jc.w & 63)) & 1ull);
        }
        for (int off = 32; off > 0; off >>= 1) cloc += __shfl_down(cloc, off);
        if (l == 0) sm.og.redc[wv] = cloc;
        __syncthreads();
        float inv = 1.0f / (float)((sm.og.redc[0] + sm.og.redc[1])
                                 + (sm.og.redc[2] + sm.og.redc[3]));
        float4* out4 = (float4*)(out_gnew + (size_t)r * KK);
        for (int c4 = t; c4 < KK / 4; c4 += 256) {
            int4 jc = idx4[c4];
            float4 o;
            o.x = ((sm.og.Tl[jc.x >> 6] >> (jc.x & 63)) & 1ull) ? inv : 0.0f;
            o.y = ((sm.og.Tl[jc.y >> 6] >> (jc.y & 63)) & 1ull) ? inv : 0.0f;
            o.z = ((sm.og.Tl[jc.z >> 6] >> (jc.z & 63)) & 1ull) ? inv : 0.0f;
            o.w = ((sm.og.Tl[jc.w >> 6] >> (jc.w & 63)) & 1ull) ? inv : 0.0f;
            out4[c4] = o;
        }
    }
}

extern "C" void kernel_launch(void* const* d_in, const int* in_sizes, int n_in,
                              void* d_out, int out_size, void* d_ws, size_t ws_size,
                              hipStream_t stream) {
    const float* g      = (const float*)d_in[0];
    const float* h      = (const float*)d_in[1];
    const float* gamma  = (const float*)d_in[2];
    const float* beta   = (const float*)d_in[3];
    const float* w_proj = (const float*)d_in[4];
    const float* b_proj = (const float*)d_in[5];
    const float* sigma1 = (const float*)d_in[6];

    char* p = (char*)d_ws;
    auto alloc = [&](size_t bytes) -> void* {
        void* q = (void*)p;
        p += (bytes + 255) & ~(size_t)255;
        return q;
    };
    double* psum    = (double*)alloc(64 * DD * 8);
    double* psq     = (double*)alloc(64 * DD * 8);
    double* mu      = (double*)alloc(DD * 8);
    double* rstd    = (double*)alloc(DD * 8);
    double* zpf     = (double*)alloc(NN * 8);
    double* Z1      = (double*)alloc(NN * 8);
    double* Z3      = (double*)alloc(NN * 8);
    int*    degi    = (int*)alloc(NN * 4);
    float*  scores  = (float*)alloc(NN * 4);
    unsigned long long* keys = (unsigned long long*)alloc(NN * 8);
    int*    idx_int = (int*)alloc(KK * 4);
    unsigned long long* B = (unsigned long long*)alloc((size_t)NN * NW * 8);
    unsigned long long* T = (unsigned long long*)alloc((size_t)NN * NW * 8);
    float*  hn      = (float*)alloc((size_t)NN * DD * 4);
    unsigned short* haT_hi = (unsigned short*)alloc((size_t)DD * NN * 2);
    unsigned short* haT_lo = (unsigned short*)alloc((size_t)DD * NN * 2);

    float* out_gnew = (float*)d_out;                       // KK*KK
    float* out_newh = out_gnew + (size_t)KK * KK;          // KK*DD
    float* out_idx  = out_newh + (size_t)KK * DD;          // KK

    hipLaunchKernelGGL(k_pre,         dim3(64 + NN),  dim3(256),  0, stream, h, g, psum, psq, B);
    hipLaunchKernelGGL(k_stats_final, dim3(1),        dim3(1024), 0, stream, psum, psq, mu, rstd);
    hipLaunchKernelGGL(k_main,        dim3(NN / 4),   dim3(256),  0, stream, h, mu, rstd, gamma, beta, B, w_proj, b_proj, hn, zpf, T, Z1, Z3, degi);
    hipLaunchKernelGGL(k_scorekeys,   dim3(16),       dim3(256),  0, stream, Z1, Z3, zpf, degi, sigma1, scores, keys);
    hipLaunchKernelGGL(k_sel,         dim3(512),      dim3(256),  0, stream, keys, scores, hn, haT_hi, haT_lo, idx_int, out_idx);
    hipLaunchKernelGGL(k_out,         dim3(256 + KK), dim3(256),  0, stream, T, idx_int, haT_hi, haT_lo, out_gnew, out_newh);
}

// Round 7
// 175.376 us; speedup vs baseline: 1.0735x; 1.0735x over previous
//
#include <hip/hip_runtime.h>
#include <math.h>

#define NN 4096
#define DD 256
#define KK 2048
#define NW 64        // u64 words per bitmask row
#define SK 8         // split-K chunks for MFMA new_h
#define KC (NN / SK) // 512 K per chunk
#define KW (KC / 32) // 16 u32 words per row-chunk

typedef float f32x4  __attribute__((ext_vector_type(4)));
typedef short bf16x8 __attribute__((ext_vector_type(8)));

// Build sorted column list for bitmask row r into LDS `cols` (one wave, lane l).
__device__ __forceinline__ int build_list(const unsigned long long* __restrict__ B, int r,
                                          int l, int* cols, int cap) {
    unsigned long long word = B[(size_t)r * NW + l];
    int pc = __popcll(word);
    int off = pc;
    for (int d = 1; d < 64; d <<= 1) {
        int n = __shfl_up(off, d);
        if (l >= d) off += n;
    }
    int total = __shfl(off, 63);
    int base = off - pc;
    while (word) {
        int b = (int)__ffsll(word) - 1;
        word &= word - 1;
        if (base < cap) cols[base] = l * 64 + b;
        ++base;
    }
    return total;
}

// ---------------- D1: column stats partials (blocks 0..63) + g bitmask (blocks 64..4159) ------
__global__ void k_pre(const float* __restrict__ h, const float* __restrict__ g,
                      double* __restrict__ psum, double* __restrict__ psq,
                      unsigned long long* __restrict__ B) {
    int blk = blockIdx.x;
    int t = threadIdx.x;   // 256
    if (blk < 64) {
        int d = t;
        int r0 = blk * 64;
        double s0=0,s1=0,s2=0,s3=0,q0=0,q1=0,q2=0,q3=0;
        for (int k = 0; k < 64; k += 4) {
            double x0 = (double)h[(size_t)(r0+k+0) * DD + d];
            double x1 = (double)h[(size_t)(r0+k+1) * DD + d];
            double x2 = (double)h[(size_t)(r0+k+2) * DD + d];
            double x3 = (double)h[(size_t)(r0+k+3) * DD + d];
            s0 += x0; q0 += x0*x0;
            s1 += x1; q1 += x1*x1;
            s2 += x2; q2 += x2*x2;
            s3 += x3; q3 += x3*x3;
        }
        psum[blk * DD + d] = (s0+s1)+(s2+s3);
        psq [blk * DD + d] = (q0+q1)+(q2+q3);
    } else {
        int i = blk - 64;
        int q = t >> 6, l = t & 63;
        const float* gr = g + (size_t)i * NN;
        unsigned long long word = 0ull;
        int lw = l & 15;
        #pragma unroll
        for (int wi = 0; wi < 16; ++wi) {
            float v = gr[(q * 16 + wi) * 64 + l];
            unsigned long long m = __ballot(v != 0.0f);
            if (wi == lw) word = m;   // lane l keeps word q*16 + (l&15)
        }
        if (l < 16) B[(size_t)i * NW + q * 16 + l] = word;
    }
}

// ---- D2: main (per-block stats finalize; wave per row: agg+norm+zpf + twohop OR) -------------
__global__ void k_main(const float* __restrict__ h, const double* __restrict__ psum,
                       const double* __restrict__ psq, const float* __restrict__ gamma,
                       const float* __restrict__ beta, const unsigned long long* __restrict__ Bm,
                       const float* __restrict__ w, const float* __restrict__ bp,
                       float* __restrict__ hn, double* __restrict__ zpf,
                       unsigned long long* __restrict__ T, double* __restrict__ Z1,
                       double* __restrict__ Z3, int* __restrict__ degi) {
    __shared__ int cols[4][136];
    __shared__ double mu_s[DD];
    __shared__ double rs_s[DD];
    int blk = blockIdx.x;
    int t = threadIdx.x;
    int wv = t >> 6, l = t & 63;
    // per-block stats finalize (128 KB L2 re-read; removes a dispatch boundary) [R4-proven]
    {
        int d = t;
        double S0=0,S1=0,Q0=0,Q1=0;
        for (int k = 0; k < 64; k += 2) {
            S0 += psum[(k)   * DD + d];
            S1 += psum[(k+1) * DD + d];
            Q0 += psq [(k)   * DD + d];
            Q1 += psq [(k+1) * DD + d];
        }
        double S = S0 + S1, Q = Q0 + Q1;
        double m   = S / (double)NN;
        double var = Q / (double)NN - m * m;
        mu_s[d] = m;
        rs_s[d] = 1.0 / sqrt(var + 1e-5);
    }
    __syncthreads();
    int r = blk * 4 + wv;
    int cnt = build_list(Bm, r, l, cols[wv], 128);
    if (cnt > 128) cnt = 128;
    const float4* h4 = (const float4*)h;
    double s0=0,s1=0,s2=0,s3=0,u0=0,u1=0,u2=0,u3=0;
    unsigned long long a0 = 0ull, a1 = 0ull;
    int j = 0;
    for (; j + 1 < cnt; j += 2) {
        int c0 = cols[wv][j], c1 = cols[wv][j + 1];
        float4 v0 = h4[(size_t)c0 * 64 + l];
        float4 v1 = h4[(size_t)c1 * 64 + l];
        a0 |= Bm[(size_t)c0 * NW + l];
        a1 |= Bm[(size_t)c1 * NW + l];
        s0 += (double)v0.x; s1 += (double)v0.y; s2 += (double)v0.z; s3 += (double)v0.w;
        u0 += (double)v1.x; u1 += (double)v1.y; u2 += (double)v1.z; u3 += (double)v1.w;
    }
    if (j < cnt) {
        int c0 = cols[wv][j];
        float4 v0 = h4[(size_t)c0 * 64 + l];
        a0 |= Bm[(size_t)c0 * NW + l];
        s0 += (double)v0.x; s1 += (double)v0.y; s2 += (double)v0.z; s3 += (double)v0.w;
    }
    T[(size_t)r * NW + l] = a0 | a1;
    s0 += u0; s1 += u1; s2 += u2; s3 += u3;
    const float4* ga4 = (const float4*)gamma;
    const float4* be4 = (const float4*)beta;
    const float4* w4  = (const float4*)w;
    double mA_x = mu_s[4*l+0], mA_y = mu_s[4*l+1], mB_x = mu_s[4*l+2], mB_y = mu_s[4*l+3];
    double rA_x = rs_s[4*l+0], rA_y = rs_s[4*l+1], rB_x = rs_s[4*l+2], rB_y = rs_s[4*l+3];
    float4 ga = ga4[l], be = be4[l], wl = w4[l];
    double inv = 1.0 / (double)cnt;
    double g0 = (s0 * inv - mA_x) * rA_x * (double)ga.x + (double)be.x;
    double g1 = (s1 * inv - mA_y) * rA_y * (double)ga.y + (double)be.y;
    double g2 = (s2 * inv - mB_x) * rB_x * (double)ga.z + (double)be.z;
    double g3 = (s3 * inv - mB_y) * rB_y * (double)ga.w + (double)be.w;
    float4 hv = h4[(size_t)r * 64 + l];
    double h0 = ((double)hv.x - mA_x) * rA_x * (double)ga.x + (double)be.x;
    double h1 = ((double)hv.y - mA_y) * rA_y * (double)ga.y + (double)be.y;
    double h2 = ((double)hv.z - mB_x) * rB_x * (double)ga.z + (double)be.z;
    double h3 = ((double)hv.w - mB_y) * rB_y * (double)ga.w + (double)be.w;
    float4 o = { (float)h0, (float)h1, (float)h2, (float)h3 };
    ((float4*)hn)[(size_t)r * 64 + l] = o;
    double z1p = (fabs(h0 - g0) + fabs(h1 - g1)) + (fabs(h2 - g2) + fabs(h3 - g3));
    double z3p = (g0 * (double)wl.x + g1 * (double)wl.y)
               + (g2 * (double)wl.z + g3 * (double)wl.w);
    double zfp = (h0 * (double)wl.x + h1 * (double)wl.y)
               + (h2 * (double)wl.z + h3 * (double)wl.w);
    for (int off = 32; off > 0; off >>= 1) {
        z1p += __shfl_down(z1p, off);
        z3p += __shfl_down(z3p, off);
        zfp += __shfl_down(zfp, off);
    }
    if (l == 0) {
        Z1[r] = z1p;
        Z3[r] = z3p + (double)bp[0];
        zpf[r] = zfp + (double)bp[0];
        degi[r] = cnt;
    }
}

// ---- D3: rank (blocks 0..255, in-block keys + 16-thread/node scan) || haT (256..511) ---------
// [R4-proven verbatim] haT_hi/haT_lo are [DD][NN] ushort (B^T layout for the MFMA B-fragment).
__global__ void k_sel(const double* __restrict__ Z1, const double* __restrict__ Z3,
                      const double* __restrict__ zpf, const int* __restrict__ degi,
                      const float* __restrict__ sigma1, const float* __restrict__ hn,
                      unsigned short* __restrict__ haT_hi, unsigned short* __restrict__ haT_lo,
                      int* __restrict__ idx_int, float* __restrict__ out_idx) {
    __shared__ unsigned long long Kl[NN];   // 32 KB; first 2 KB aliased as double red[256]
    double* red = (double*)Kl;
    int bid = blockIdx.x;
    int t = threadIdx.x;   // 256
    int wv = t >> 6, l = t & 63;
    // global softmax stats over Z3 (deterministic, identical in every block)
    double mx = -1e300;
    for (int k = 0; k < 16; ++k) mx = fmax(mx, Z3[t + 256 * k]);
    red[t] = mx;
    __syncthreads();
    for (int s = 128; s > 0; s >>= 1) {
        if (t < s) red[t] = fmax(red[t], red[t + s]);
        __syncthreads();
    }
    double M = red[0];
    __syncthreads();
    double se = 0.0;
    for (int k = 0; k < 16; ++k) se += exp(Z3[t + 256 * k] - M);
    red[t] = se;
    __syncthreads();
    for (int s = 128; s > 0; s >>= 1) {
        if (t < s) red[t] += red[t + s];
        __syncthreads();
    }
    double sum = red[0];
    double s1 = (double)sigma1[0];
    __syncthreads();   // done with red; Kl may be overwritten below
    if (bid < 256) {
        // build all 4096 keys (16 nodes/thread)
        for (int i = t; i < NN; i += 256) {
            double pg = exp(Z3[i] - M) / sum;
            double pl = 1.0 / (1.0 + exp(-(Z1[i] + (double)degi[i])));
            double pt = 1.0 / (1.0 + exp(-(pl + pg)));
            double pf = 1.0 / (1.0 + exp(-zpf[i]));
            float sc = (float)(s1 * pt + (1.0 - s1) * pf);
            unsigned int b2 = __float_as_uint(sc);
            unsigned int ka = (b2 & 0x80000000u) ? ~b2 : (b2 ^ 0x80000000u);
            Kl[i] = ((unsigned long long)(~ka) << 32) | (unsigned int)i;
        }
        __syncthreads();
        // rank: 16 threads per node, each scans 256 keys
        int il = t >> 4, sub = t & 15;
        int i = bid * 16 + il;
        unsigned long long ki = Kl[i];
        int c0 = 0, c1 = 0, c2 = 0, c3 = 0;
        for (int jj = 0; jj < 256; jj += 4) {
            int jx = sub + (jj << 4);
            c0 += (Kl[jx]      < ki) ? 1 : 0;
            c1 += (Kl[jx + 16] < ki) ? 1 : 0;
            c2 += (Kl[jx + 32] < ki) ? 1 : 0;
            c3 += (Kl[jx + 48] < ki) ? 1 : 0;
        }
        int cnt = (c0 + c1) + (c2 + c3);
        for (int off = 8; off > 0; off >>= 1) cnt += __shfl_down(cnt, off, 16);
        if (sub == 0 && cnt < KK) {   // exact bijection: keys are unique
            idx_int[cnt] = i;
            out_idx[cnt] = (float)i;
        }
    } else {
        // haT: 256 blocks = 64 node-groups x 4 d-quarters; lane = node (coalesced stores)
        int bb = bid - 256;
        int ng = bb & 63, dq = bb >> 6;
        int node = ng * 64 + l;
        double pg = exp(Z3[node] - M) / sum;
        double pl = 1.0 / (1.0 + exp(-(Z1[node] + (double)degi[node])));
        double pt = 1.0 / (1.0 + exp(-(pl + pg)));
        double pf = 1.0 / (1.0 + exp(-zpf[node]));
        float sc = (float)(s1 * pt + (1.0 - s1) * pf);
        const float* hr = hn + (size_t)node * DD;
        for (int d = dq * 64 + wv; d < (dq + 1) * 64; d += 4) {
            float x = hr[d] * sc;
            unsigned int xb = __float_as_uint(x);
            unsigned int hb = xb & 0xFFFF0000u;
            float lo = x - __uint_as_float(hb);
            unsigned int lb = __float_as_uint(lo);
            haT_hi[(size_t)d * NN + node] = (unsigned short)(hb >> 16);
            haT_lo[(size_t)d * NN + node] = (unsigned short)(lb >> 16);
        }
    }
}

// ---- D4: split-K(8) MFMA new_h partials (blocks 0..511, 2/CU) ||
//          g_new rows w/ in-block rowsum (blocks 512..2559) ----------------------------------
__global__ void k_out(const unsigned long long* __restrict__ T, const int* __restrict__ idx_int,
                      const unsigned short* __restrict__ haT_hi,
                      const unsigned short* __restrict__ haT_lo,
                      float* __restrict__ part, float* __restrict__ out_gnew) {
    union Sm {
        struct { unsigned long long Tl[NW]; int redc[4]; } og;
        struct { int ids[128]; unsigned int Ab[128][KW + 1]; } nh;   // 9.2 KB
    };
    __shared__ Sm sm;
    int bid = blockIdx.x;
    int t = threadIdx.x;   // 256
    int wv = t >> 6, l = t & 63;
    if (bid < 512) {
        // ---- new_h partial: 16 row-stripes x 4 col-blocks x SK(8) k-chunks of K=512 ----
        int rs = bid & 15, cb = (bid >> 4) & 3, kc = bid >> 6;   // kc in 0..7
        if (t < 128) sm.nh.ids[t] = idx_int[rs * 128 + t];
        __syncthreads();
        for (int i = t; i < 128 * KW; i += 256) {
            int row = i >> 4, wd = i & (KW - 1);
            sm.nh.Ab[row][wd] =
                ((const unsigned int*)(T + (size_t)sm.nh.ids[row] * NW))[kc * KW + wd];
        }
        __syncthreads();
        int lm = l & 15, lg = l >> 4;
        int row_base = (wv & 1) * 64;                  // wave tile: 64 rows x 32 cols
        int col_base = cb * 64 + (wv >> 1) * 32;
        f32x4 acc[4][2];
        #pragma unroll
        for (int m = 0; m < 4; ++m) { acc[m][0] = (f32x4)0.0f; acc[m][1] = (f32x4)0.0f; }
        const unsigned short* ph0 = haT_hi + (size_t)(col_base + lm) * NN + kc * KC + lg * 8;
        const unsigned short* ph1 = ph0 + (size_t)16 * NN;
        const unsigned short* pl0 = haT_lo + (size_t)(col_base + lm) * NN + kc * KC + lg * 8;
        const unsigned short* pl1 = pl0 + (size_t)16 * NN;
        #pragma unroll 2
        for (int ks = 0; ks < KW; ++ks) {
            bf16x8 bh0 = *(const bf16x8*)(ph0 + ks * 32);
            bf16x8 bh1 = *(const bf16x8*)(ph1 + ks * 32);
            bf16x8 bl0 = *(const bf16x8*)(pl0 + ks * 32);
            bf16x8 bl1 = *(const bf16x8*)(pl1 + ks * 32);
            #pragma unroll
            for (int m = 0; m < 4; ++m) {
                unsigned int bits = sm.nh.Ab[row_base + m * 16 + lm][ks];
                unsigned int b8 = (bits >> (8 * lg)) & 0xFFu;
                union { unsigned int u[4]; bf16x8 v; } au;
                au.u[0] = ((b8 & 1u)        ? 0x3F80u : 0u) | ((b8 & 2u)   ? 0x3F800000u : 0u);
                au.u[1] = (((b8 >> 2) & 1u) ? 0x3F80u : 0u) | ((b8 & 8u)   ? 0x3F800000u : 0u);
                au.u[2] = (((b8 >> 4) & 1u) ? 0x3F80u : 0u) | ((b8 & 32u)  ? 0x3F800000u : 0u);
                au.u[3] = (((b8 >> 6) & 1u) ? 0x3F80u : 0u) | ((b8 & 128u) ? 0x3F800000u : 0u);
                bf16x8 a = au.v;
                acc[m][0] = __builtin_amdgcn_mfma_f32_16x16x32_bf16(a, bh0, acc[m][0], 0, 0, 0);
                acc[m][1] = __builtin_amdgcn_mfma_f32_16x16x32_bf16(a, bh1, acc[m][1], 0, 0, 0);
                acc[m][0] = __builtin_amdgcn_mfma_f32_16x16x32_bf16(a, bl0, acc[m][0], 0, 0, 0);
                acc[m][1] = __builtin_amdgcn_mfma_f32_16x16x32_bf16(a, bl1, acc[m][1], 0, 0, 0);
            }
        }
        // C/D layout (HW-verified): col = l&15, row = (l>>4)*4 + reg
        float* pp = part + (size_t)kc * ((size_t)KK * DD);
        #pragma unroll
        for (int m = 0; m < 4; ++m) {
            int row0 = rs * 128 + row_base + m * 16 + lg * 4;
            #pragma unroll
            for (int n = 0; n < 2; ++n) {
                int col = col_base + n * 16 + lm;
                #pragma unroll
                for (int rr = 0; rr < 4; ++rr)
                    pp[(size_t)(row0 + rr) * DD + col] = acc[m][n][rr];
            }
        }
    } else {
        // ---- g_new row: pass1 in-block count over selected cols, pass2 write ----
        int r = bid - 512;
        if (t < NW) sm.og.Tl[t] = T[(size_t)idx_int[r] * NW + t];
        __syncthreads();
        const int4* idx4 = (const int4*)idx_int;
        int cloc = 0;
        for (int c4 = t; c4 < KK / 4; c4 += 256) {
            int4 jc = idx4[c4];
            cloc += (int)((sm.og.Tl[jc.x >> 6] >> (jc.x & 63)) & 1ull)
                  + (int)((sm.og.Tl[jc.y >> 6] >> (jc.y & 63)) & 1ull)
                  + (int)((sm.og.Tl[jc.z >> 6] >> (jc.z & 63)) & 1ull)
                  + (int)((sm.og.Tl[jc.w >> 6] >> (jc.w & 63)) & 1ull);
        }
        for (int off = 32; off > 0; off >>= 1) cloc += __shfl_down(cloc, off);
        if (l == 0) sm.og.redc[wv] = cloc;
        __syncthreads();
        float inv = 1.0f / (float)((sm.og.redc[0] + sm.og.redc[1])
                                 + (sm.og.redc[2] + sm.og.redc[3]));
        float4* out4 = (float4*)(out_gnew + (size_t)r * KK);
        for (int c4 = t; c4 < KK / 4; c4 += 256) {
            int4 jc = idx4[c4];
            float4 o;
            o.x = ((sm.og.Tl[jc.x >> 6] >> (jc.x & 63)) & 1ull) ? inv : 0.0f;
            o.y = ((sm.og.Tl[jc.y >> 6] >> (jc.y & 63)) & 1ull) ? inv : 0.0f;
            o.z = ((sm.og.Tl[jc.z >> 6] >> (jc.z & 63)) & 1ull) ? inv : 0.0f;
            o.w = ((sm.og.Tl[jc.w >> 6] >> (jc.w & 63)) & 1ull) ? inv : 0.0f;
            out4[c4] = o;
        }
    }
}

// ---------------- D5: deterministic split-K reduce: out_newh = sum of 8 partials --------------
__global__ void k_red(const float* __restrict__ part, float* __restrict__ out_newh) {
    int t = threadIdx.x;   // 256
    size_t off = (size_t)blockIdx.x * 1024 + (size_t)t * 4;
    const size_t stride = (size_t)KK * DD;
    float4 s0 = *(const float4*)(part + off);
    float4 s1 = *(const float4*)(part + off + stride);
    float4 s2 = *(const float4*)(part + off + 2 * stride);
    float4 s3 = *(const float4*)(part + off + 3 * stride);
    float4 s4 = *(const float4*)(part + off + 4 * stride);
    float4 s5 = *(const float4*)(part + off + 5 * stride);
    float4 s6 = *(const float4*)(part + off + 6 * stride);
    float4 s7 = *(const float4*)(part + off + 7 * stride);
    float4 o;
    o.x = ((s0.x + s1.x) + (s2.x + s3.x)) + ((s4.x + s5.x) + (s6.x + s7.x));
    o.y = ((s0.y + s1.y) + (s2.y + s3.y)) + ((s4.y + s5.y) + (s6.y + s7.y));
    o.z = ((s0.z + s1.z) + (s2.z + s3.z)) + ((s4.z + s5.z) + (s6.z + s7.z));
    o.w = ((s0.w + s1.w) + (s2.w + s3.w)) + ((s4.w + s5.w) + (s6.w + s7.w));
    *(float4*)(out_newh + off) = o;
}

extern "C" void kernel_launch(void* const* d_in, const int* in_sizes, int n_in,
                              void* d_out, int out_size, void* d_ws, size_t ws_size,
                              hipStream_t stream) {
    const float* g      = (const float*)d_in[0];
    const float* h      = (const float*)d_in[1];
    const float* gamma  = (const float*)d_in[2];
    const float* beta   = (const float*)d_in[3];
    const float* w_proj = (const float*)d_in[4];
    const float* b_proj = (const float*)d_in[5];
    const float* sigma1 = (const float*)d_in[6];

    char* p = (char*)d_ws;
    auto alloc = [&](size_t bytes) -> void* {
        void* q = (void*)p;
        p += (bytes + 255) & ~(size_t)255;
        return q;
    };
    double* psum    = (double*)alloc(64 * DD * 8);
    double* psq     = (double*)alloc(64 * DD * 8);
    double* zpf     = (double*)alloc(NN * 8);
    double* Z1      = (double*)alloc(NN * 8);
    double* Z3      = (double*)alloc(NN * 8);
    int*    degi    = (int*)alloc(NN * 4);
    int*    idx_int = (int*)alloc(KK * 4);
    unsigned long long* B = (unsigned long long*)alloc((size_t)NN * NW * 8);
    unsigned long long* T = (unsigned long long*)alloc((size_t)NN * NW * 8);
    float*  hn      = (float*)alloc((size_t)NN * DD * 4);
    unsigned short* haT_hi = (unsigned short*)alloc((size_t)DD * NN * 2);
    unsigned short* haT_lo = (unsigned short*)alloc((size_t)DD * NN * 2);
    float*  part    = (float*)alloc((size_t)SK * KK * DD * 4);

    float* out_gnew = (float*)d_out;                       // KK*KK
    float* out_newh = out_gnew + (size_t)KK * KK;          // KK*DD
    float* out_idx  = out_newh + (size_t)KK * DD;          // KK

    hipLaunchKernelGGL(k_pre,  dim3(64 + NN),  dim3(256), 0, stream, h, g, psum, psq, B);
    hipLaunchKernelGGL(k_main, dim3(NN / 4),   dim3(256), 0, stream, h, psum, psq, gamma, beta, B, w_proj, b_proj, hn, zpf, T, Z1, Z3, degi);
    hipLaunchKernelGGL(k_sel,  dim3(512),      dim3(256), 0, stream, Z1, Z3, zpf, degi, sigma1, hn, haT_hi, haT_lo, idx_int, out_idx);
    hipLaunchKernelGGL(k_out,  dim3(512 + KK), dim3(256), 0, stream, T, idx_int, haT_hi, haT_lo, part, out_gnew);
    hipLaunchKernelGGL(k_red,  dim3(512),      dim3(256), 0, stream, part, out_newh);
}

// Round 8
// 170.270 us; speedup vs baseline: 1.1057x; 1.0300x over previous
//
#include <hip/hip_runtime.h>
#include <math.h>

#define NN 4096
#define DD 256
#define KK 2048
#define NW 64        // u64 words per bitmask row
#define SK 4         // split-K chunks for MFMA new_h
#define KC (NN / SK) // 1024 K per chunk
#define KW (KC / 32) // 32 u32 words per row-chunk

typedef float f32x4  __attribute__((ext_vector_type(4)));
typedef short bf16x8 __attribute__((ext_vector_type(8)));

// Build sorted column list for bitmask row r into LDS `cols` (one wave, lane l).
__device__ __forceinline__ int build_list(const unsigned long long* __restrict__ B, int r,
                                          int l, int* cols, int cap) {
    unsigned long long word = B[(size_t)r * NW + l];
    int pc = __popcll(word);
    int off = pc;
    for (int d = 1; d < 64; d <<= 1) {
        int n = __shfl_up(off, d);
        if (l >= d) off += n;
    }
    int total = __shfl(off, 63);
    int base = off - pc;
    while (word) {
        int b = (int)__ffsll(word) - 1;
        word &= word - 1;
        if (base < cap) cols[base] = l * 64 + b;
        ++base;
    }
    return total;
}

// ---------------- fused: column stats partials (blocks 0..63) + g bitmask (blocks 64..4159) ----
// bitmask packing via __ballot: word w bit b <-> column w*64+b.
__global__ void k_pre(const float* __restrict__ h, const float* __restrict__ g,
                      double* __restrict__ psum, double* __restrict__ psq,
                      unsigned long long* __restrict__ B) {
    int blk = blockIdx.x;
    int t = threadIdx.x;   // 256
    if (blk < 64) {
        int d = t;
        int r0 = blk * 64;
        double s0=0,s1=0,s2=0,s3=0,q0=0,q1=0,q2=0,q3=0;
        for (int k = 0; k < 64; k += 4) {
            double x0 = (double)h[(size_t)(r0+k+0) * DD + d];
            double x1 = (double)h[(size_t)(r0+k+1) * DD + d];
            double x2 = (double)h[(size_t)(r0+k+2) * DD + d];
            double x3 = (double)h[(size_t)(r0+k+3) * DD + d];
            s0 += x0; q0 += x0*x0;
            s1 += x1; q1 += x1*x1;
            s2 += x2; q2 += x2*x2;
            s3 += x3; q3 += x3*x3;
        }
        psum[blk * DD + d] = (s0+s1)+(s2+s3);
        psq [blk * DD + d] = (q0+q1)+(q2+q3);
    } else {
        int i = blk - 64;
        int q = t >> 6, l = t & 63;
        const float* gr = g + (size_t)i * NN;
        unsigned long long word = 0ull;
        int lw = l & 15;
        #pragma unroll
        for (int wi = 0; wi < 16; ++wi) {
            float v = gr[(q * 16 + wi) * 64 + l];
            unsigned long long m = __ballot(v != 0.0f);
            if (wi == lw) word = m;   // lane l keeps word q*16 + (l&15)
        }
        if (l < 16) B[(size_t)i * NW + q * 16 + l] = word;
    }
}

// ---------------- stats final: 1 block x 1024 ----------------
__global__ void k_stats_final(const double* __restrict__ psum, const double* __restrict__ psq,
                              double* __restrict__ mu, double* __restrict__ rstd) {
    __shared__ double rs[4][DD];
    __shared__ double rq[4][DD];
    int t = threadIdx.x;
    int d = t & (DD - 1);
    int q = t >> 8;
    double s0=0,s1=0,q0=0,q1=0;
    int b0 = q * 16;
    for (int k = 0; k < 16; k += 2) {
        s0 += psum[(b0+k)   * DD + d];
        s1 += psum[(b0+k+1) * DD + d];
        q0 += psq [(b0+k)   * DD + d];
        q1 += psq [(b0+k+1) * DD + d];
    }
    rs[q][d] = s0 + s1;
    rq[q][d] = q0 + q1;
    __syncthreads();
    if (q == 0) {
        double S  = (rs[0][d]+rs[1][d]) + (rs[2][d]+rs[3][d]);
        double Q  = (rq[0][d]+rq[1][d]) + (rq[2][d]+rq[3][d]);
        double m  = S / (double)NN;
        double var = Q / (double)NN - m * m;
        mu[d]   = m;
        rstd[d] = 1.0 / sqrt(var + 1e-5);
    }
}

// ---- fused main: wave per row, ONE list build feeding BOTH agg+norm+zpf AND twohop OR --------
__global__ void k_main(const float* __restrict__ h, const double* __restrict__ mu,
                       const double* __restrict__ rstd, const float* __restrict__ gamma,
                       const float* __restrict__ beta, const unsigned long long* __restrict__ Bm,
                       const float* __restrict__ w, const float* __restrict__ bp,
                       float* __restrict__ hn, double* __restrict__ zpf,
                       unsigned long long* __restrict__ T, double* __restrict__ Z1,
                       double* __restrict__ Z3, int* __restrict__ degi) {
    __shared__ int cols[4][136];
    int blk = blockIdx.x;
    int t = threadIdx.x;
    int wv = t >> 6, l = t & 63;
    int r = blk * 4 + wv;
    int cnt = build_list(Bm, r, l, cols[wv], 128);
    if (cnt > 128) cnt = 128;
    const float4* h4 = (const float4*)h;
    double s0=0,s1=0,s2=0,s3=0,u0=0,u1=0,u2=0,u3=0;
    unsigned long long a0 = 0ull, a1 = 0ull;
    int j = 0;
    for (; j + 1 < cnt; j += 2) {
        int c0 = cols[wv][j], c1 = cols[wv][j + 1];
        float4 v0 = h4[(size_t)c0 * 64 + l];
        float4 v1 = h4[(size_t)c1 * 64 + l];
        a0 |= Bm[(size_t)c0 * NW + l];
        a1 |= Bm[(size_t)c1 * NW + l];
        s0 += (double)v0.x; s1 += (double)v0.y; s2 += (double)v0.z; s3 += (double)v0.w;
        u0 += (double)v1.x; u1 += (double)v1.y; u2 += (double)v1.z; u3 += (double)v1.w;
    }
    if (j < cnt) {
        int c0 = cols[wv][j];
        float4 v0 = h4[(size_t)c0 * 64 + l];
        a0 |= Bm[(size_t)c0 * NW + l];
        s0 += (double)v0.x; s1 += (double)v0.y; s2 += (double)v0.z; s3 += (double)v0.w;
    }
    T[(size_t)r * NW + l] = a0 | a1;
    s0 += u0; s1 += u1; s2 += u2; s3 += u3;
    const double2* mu2 = (const double2*)mu;
    const double2* rs2 = (const double2*)rstd;
    const float4*  ga4 = (const float4*)gamma;
    const float4*  be4 = (const float4*)beta;
    const float4*  w4  = (const float4*)w;
    double2 mA = mu2[2*l], mB = mu2[2*l+1];
    double2 rA = rs2[2*l], rB = rs2[2*l+1];
    float4 ga = ga4[l], be = be4[l], wl = w4[l];
    double inv = 1.0 / (double)cnt;
    double g0 = (s0 * inv - mA.x) * rA.x * (double)ga.x + (double)be.x;
    double g1 = (s1 * inv - mA.y) * rA.y * (double)ga.y + (double)be.y;
    double g2 = (s2 * inv - mB.x) * rB.x * (double)ga.z + (double)be.z;
    double g3 = (s3 * inv - mB.y) * rB.y * (double)ga.w + (double)be.w;
    float4 hv = h4[(size_t)r * 64 + l];
    double h0 = ((double)hv.x - mA.x) * rA.x * (double)ga.x + (double)be.x;
    double h1 = ((double)hv.y - mA.y) * rA.y * (double)ga.y + (double)be.y;
    double h2 = ((double)hv.z - mB.x) * rB.x * (double)ga.z + (double)be.z;
    double h3 = ((double)hv.w - mB.y) * rB.y * (double)ga.w + (double)be.w;
    float4 o = { (float)h0, (float)h1, (float)h2, (float)h3 };
    ((float4*)hn)[(size_t)r * 64 + l] = o;
    double z1p = (fabs(h0 - g0) + fabs(h1 - g1)) + (fabs(h2 - g2) + fabs(h3 - g3));
    double z3p = (g0 * (double)wl.x + g1 * (double)wl.y)
               + (g2 * (double)wl.z + g3 * (double)wl.w);
    double zfp = (h0 * (double)wl.x + h1 * (double)wl.y)
               + (h2 * (double)wl.z + h3 * (double)wl.w);
    for (int off = 32; off > 0; off >>= 1) {
        z1p += __shfl_down(z1p, off);
        z3p += __shfl_down(z3p, off);
        zfp += __shfl_down(zfp, off);
    }
    if (l == 0) {
        Z1[r] = z1p;
        Z3[r] = z3p + (double)bp[0];
        zpf[r] = zfp + (double)bp[0];
        degi[r] = cnt;
    }
}

// ---------------- scores: each of 16 blocks redundantly reduces softmax stats (deterministic) ----
__global__ void k_scorekeys(const double* __restrict__ Z1, const double* __restrict__ Z3,
                            const double* __restrict__ zpf, const int* __restrict__ degi,
                            const float* __restrict__ sigma1, float* __restrict__ scores,
                            unsigned long long* __restrict__ keys) {
    __shared__ double red[256];
    int t = threadIdx.x;
    double mx = -1e300;
    for (int k = 0; k < 16; ++k) mx = fmax(mx, Z3[t + 256 * k]);
    red[t] = mx;
    __syncthreads();
    for (int s = 128; s > 0; s >>= 1) {
        if (t < s) red[t] = fmax(red[t], red[t + s]);
        __syncthreads();
    }
    double M = red[0];
    __syncthreads();
    double se = 0.0;
    for (int k = 0; k < 16; ++k) se += exp(Z3[t + 256 * k] - M);
    red[t] = se;
    __syncthreads();
    for (int s = 128; s > 0; s >>= 1) {
        if (t < s) red[t] += red[t + s];
        __syncthreads();
    }
    double sum = red[0];
    int i = blockIdx.x * 256 + t;
    double s1 = (double)sigma1[0];
    double pg = exp(Z3[i] - M) / sum;
    double pl = 1.0 / (1.0 + exp(-(Z1[i] + (double)degi[i])));
    double pt = 1.0 / (1.0 + exp(-(pl + pg)));
    double pf = 1.0 / (1.0 + exp(-zpf[i]));
    float sc = (float)(s1 * pt + (1.0 - s1) * pf);
    scores[i] = sc;
    unsigned int b2 = __float_as_uint(sc);
    unsigned int ka = (b2 & 0x80000000u) ? ~b2 : (b2 ^ 0x80000000u);  // ascending order key
    keys[i] = ((unsigned long long)(~ka) << 32) | (unsigned int)i;    // asc = desc score, asc idx
}

// ---------------- rank-by-counting top-k scatter (no atomics) ----------------
__global__ void k_rank(const unsigned long long* __restrict__ keys, int* __restrict__ idx_int,
                       float* __restrict__ out_idx) {
    __shared__ unsigned long long Kl[NN];
    int t = threadIdx.x;
    for (int i = t; i < NN; i += 256) Kl[i] = keys[i];
    __syncthreads();
    int il = t >> 4, sub = t & 15;
    int i = blockIdx.x * 16 + il;
    unsigned long long ki = Kl[i];
    int c0 = 0, c1 = 0, c2 = 0, c3 = 0;
    for (int jj = 0; jj < 256; jj += 4) {
        int j = sub + (jj << 4);
        c0 += (Kl[j]      < ki) ? 1 : 0;
        c1 += (Kl[j + 16] < ki) ? 1 : 0;
        c2 += (Kl[j + 32] < ki) ? 1 : 0;
        c3 += (Kl[j + 48] < ki) ? 1 : 0;
    }
    int cnt = (c0 + c1) + (c2 + c3);
    for (int off = 8; off > 0; off >>= 1) cnt += __shfl_down(cnt, off, 16);
    if (sub == 0 && cnt < KK) {   // exact bijection: keys are unique
        idx_int[cnt] = i;
        out_idx[cnt] = (float)i;
    }
}

// ---- fused mid: rowsum (blocks 0..127) + h_att split/transpose to bf16 hi/lo (128..383) ------
// haT_hi/haT_lo are [DD][NN] ushort (B^T layout for the MFMA B-fragment).
__global__ void k_mid(const unsigned long long* __restrict__ T, const int* __restrict__ idx_int,
                      const float* __restrict__ scores, const float* __restrict__ hn,
                      float* __restrict__ inv_rs, unsigned short* __restrict__ haT_hi,
                      unsigned short* __restrict__ haT_lo) {
    int blk = blockIdx.x;
    int t = threadIdx.x;   // 256
    if (blk < 128) {
        __shared__ unsigned long long Sl[NW];
        if (t < NW) Sl[t] = 0ull;
        __syncthreads();
        for (int j = t; j < KK; j += 256) {
            int ii = idx_int[j];
            atomicOr(&Sl[ii >> 6], 1ull << (ii & 63));
        }
        __syncthreads();
        int wv = t >> 6, l = t & 63;
        unsigned long long sw = Sl[l];
        #pragma unroll
        for (int k = 0; k < 4; ++k) {
            int j = blk * 16 + wv * 4 + k;       // position in idx (0..2047)
            int r = idx_int[j];
            int c = (int)__popcll(T[(size_t)r * NW + l] & sw);
            for (int off = 32; off > 0; off >>= 1) c += __shfl_down(c, off);
            if (l == 0) inv_rs[j] = 1.0f / (float)c;
        }
    } else {
        // 256 blocks: 64 node-groups x 4 d-quarters; lane = node (coalesced 128B ushort writes)
        int bb = blk - 128;
        int ng = bb & 63, dq = bb >> 6;
        int wv = t >> 6, l = t & 63;
        int node = ng * 64 + l;
        float sc = scores[node];
        const float* hr = hn + (size_t)node * DD;
        for (int d = dq * 64 + wv; d < (dq + 1) * 64; d += 4) {
            float x = hr[d] * sc;
            unsigned int xb = __float_as_uint(x);
            unsigned int hb = xb & 0xFFFF0000u;
            float lo = x - __uint_as_float(hb);
            unsigned int lb = __float_as_uint(lo);
            haT_hi[(size_t)d * NN + node] = (unsigned short)(hb >> 16);
            haT_lo[(size_t)d * NN + node] = (unsigned short)(lb >> 16);
        }
    }
}

// ---- new_h via dense MFMA: C[2048x256] = A_hat(0/1 bits) @ h_att (bf16 hi+lo split) ----------
// grid = 16 row-stripes x 4 col-blocks x SK k-chunks = 256 blocks, 256 threads.
__global__ void __launch_bounds__(256, 1)
k_nh(const unsigned long long* __restrict__ T, const int* __restrict__ idx_int,
     const unsigned short* __restrict__ haT_hi, const unsigned short* __restrict__ haT_lo,
     float* __restrict__ part) {
    __shared__ int ids[128];
    __shared__ unsigned int Ab[128][KW + 1];   // padded: bank-conflict-free column reads
    int blk = blockIdx.x;
    int rs = blk & 15, cb = (blk >> 4) & 3, kc = blk >> 6;
    int t = threadIdx.x;
    if (t < 128) ids[t] = idx_int[rs * 128 + t];
    __syncthreads();
    for (int i = t; i < 128 * KW; i += 256) {
        int row = i >> 5, w = i & (KW - 1);
        Ab[row][w] = ((const unsigned int*)(T + (size_t)ids[row] * NW))[kc * KW + w];
    }
    __syncthreads();
    int wv = t >> 6, l = t & 63;
    int lm = l & 15, lg = l >> 4;
    int row_base = (wv & 1) * 64;                  // wave tile: 64 rows x 32 cols
    int col_base = cb * 64 + (wv >> 1) * 32;
    f32x4 acc[4][2];
    #pragma unroll
    for (int m = 0; m < 4; ++m) { acc[m][0] = (f32x4)0.0f; acc[m][1] = (f32x4)0.0f; }
    const unsigned short* ph0 = haT_hi + (size_t)(col_base + lm) * NN + kc * KC + lg * 8;
    const unsigned short* ph1 = ph0 + (size_t)16 * NN;
    const unsigned short* pl0 = haT_lo + (size_t)(col_base + lm) * NN + kc * KC + lg * 8;
    const unsigned short* pl1 = pl0 + (size_t)16 * NN;
    #pragma unroll 2
    for (int ks = 0; ks < KW; ++ks) {
        bf16x8 bh0 = *(const bf16x8*)(ph0 + ks * 32);
        bf16x8 bh1 = *(const bf16x8*)(ph1 + ks * 32);
        bf16x8 bl0 = *(const bf16x8*)(pl0 + ks * 32);
        bf16x8 bl1 = *(const bf16x8*)(pl1 + ks * 32);
        #pragma unroll
        for (int m = 0; m < 4; ++m) {
            unsigned int bits = Ab[row_base + m * 16 + lm][ks];
            unsigned int b8 = (bits >> (8 * lg)) & 0xFFu;
            union { unsigned int u[4]; bf16x8 v; } au;
            au.u[0] = ((b8 & 1u)        ? 0x3F80u : 0u) | ((b8 & 2u)   ? 0x3F800000u : 0u);
            au.u[1] = (((b8 >> 2) & 1u) ? 0x3F80u : 0u) | ((b8 & 8u)   ? 0x3F800000u : 0u);
            au.u[2] = (((b8 >> 4) & 1u) ? 0x3F80u : 0u) | ((b8 & 32u)  ? 0x3F800000u : 0u);
            au.u[3] = (((b8 >> 6) & 1u) ? 0x3F80u : 0u) | ((b8 & 128u) ? 0x3F800000u : 0u);
            bf16x8 a = au.v;
            acc[m][0] = __builtin_amdgcn_mfma_f32_16x16x32_bf16(a, bh0, acc[m][0], 0, 0, 0);
            acc[m][1] = __builtin_amdgcn_mfma_f32_16x16x32_bf16(a, bh1, acc[m][1], 0, 0, 0);
            acc[m][0] = __builtin_amdgcn_mfma_f32_16x16x32_bf16(a, bl0, acc[m][0], 0, 0, 0);
            acc[m][1] = __builtin_amdgcn_mfma_f32_16x16x32_bf16(a, bl1, acc[m][1], 0, 0, 0);
        }
    }
    // C/D layout (HW-verified): col = l&15, row = (l>>4)*4 + reg
    float* pp = part + (size_t)kc * ((size_t)KK * DD);
    #pragma unroll
    for (int m = 0; m < 4; ++m) {
        int row0 = rs * 128 + row_base + m * 16 + lg * 4;
        #pragma unroll
        for (int n = 0; n < 2; ++n) {
            int col = col_base + n * 16 + lm;
            #pragma unroll
            for (int r = 0; r < 4; ++r)
                pp[(size_t)(row0 + r) * DD + col] = acc[m][n][r];
        }
    }
}

// ---------------- fused outputs: g_new (blocks 0..2047) + split-K reduce of new_h (2048..2559) -
__global__ void k_out(const unsigned long long* __restrict__ T, const int* __restrict__ idx_int,
                      const float* __restrict__ inv_rs, const float* __restrict__ part,
                      float* __restrict__ out_gnew, float* __restrict__ out_newh) {
    __shared__ unsigned long long Tl[NW];
    int blk = blockIdx.x;
    int t = threadIdx.x;   // 256
    if (blk < KK) {
        // ---- g_new row ----
        int r = blk;
        if (t < NW) Tl[t] = T[(size_t)idx_int[r] * NW + t];
        __syncthreads();
        const int4*   idx4 = (const int4*)idx_int;
        const float4* irs4 = (const float4*)inv_rs;
        float4* out4 = (float4*)(out_gnew + (size_t)r * KK);
        for (int c4 = t; c4 < KK / 4; c4 += 256) {
            int4 jc = idx4[c4];
            float4 iv = irs4[c4];
            float4 o;
            o.x = ((Tl[jc.x >> 6] >> (jc.x & 63)) & 1ull) ? iv.x : 0.0f;
            o.y = ((Tl[jc.y >> 6] >> (jc.y & 63)) & 1ull) ? iv.y : 0.0f;
            o.z = ((Tl[jc.z >> 6] >> (jc.z & 63)) & 1ull) ? iv.z : 0.0f;
            o.w = ((Tl[jc.w >> 6] >> (jc.w & 63)) & 1ull) ? iv.w : 0.0f;
            out4[c4] = o;
        }
    } else {
        // ---- deterministic split-K reduction: out_newh = sum of SK partials ----
        size_t off = (size_t)(blk - KK) * 1024 + (size_t)t * 4;
        const size_t stride = (size_t)KK * DD;
        float4 s0 = *(const float4*)(part + off);
        float4 s1 = *(const float4*)(part + off + stride);
        float4 s2 = *(const float4*)(part + off + 2 * stride);
        float4 s3 = *(const float4*)(part + off + 3 * stride);
        float4 o;
        o.x = (s0.x + s1.x) + (s2.x + s3.x);
        o.y = (s0.y + s1.y) + (s2.y + s3.y);
        o.z = (s0.z + s1.z) + (s2.z + s3.z);
        o.w = (s0.w + s1.w) + (s2.w + s3.w);
        *(float4*)(out_newh + off) = o;
    }
}

extern "C" void kernel_launch(void* const* d_in, const int* in_sizes, int n_in,
                              void* d_out, int out_size, void* d_ws, size_t ws_size,
                              hipStream_t stream) {
    const float* g      = (const float*)d_in[0];
    const float* h      = (const float*)d_in[1];
    const float* gamma  = (const float*)d_in[2];
    const float* beta   = (const float*)d_in[3];
    const float* w_proj = (const float*)d_in[4];
    const float* b_proj = (const float*)d_in[5];
    const float* sigma1 = (const float*)d_in[6];

    char* p = (char*)d_ws;
    auto alloc = [&](size_t bytes) -> void* {
        void* q = (void*)p;
        p += (bytes + 255) & ~(size_t)255;
        return q;
    };
    double* mu      = (double*)alloc(DD * 8);
    double* rstd    = (double*)alloc(DD * 8);
    double* psum    = (double*)alloc(64 * DD * 8);
    double* psq     = (double*)alloc(64 * DD * 8);
    double* zpf     = (double*)alloc(NN * 8);
    double* Z1      = (double*)alloc(NN * 8);
    double* Z3      = (double*)alloc(NN * 8);
    int*    degi    = (int*)alloc(NN * 4);
    float*  scores  = (float*)alloc(NN * 4);
    unsigned long long* keys = (unsigned long long*)alloc(NN * 8);
    int*    idx_int = (int*)alloc(KK * 4);
    float*  inv_rs  = (float*)alloc(KK * 4);
    unsigned long long* B = (unsigned long long*)alloc((size_t)NN * NW * 8);
    unsigned long long* T = (unsigned long long*)alloc((size_t)NN * NW * 8);
    float*  hn      = (float*)alloc((size_t)NN * DD * 4);
    unsigned short* haT_hi = (unsigned short*)alloc((size_t)DD * NN * 2);
    unsigned short* haT_lo = (unsigned short*)alloc((size_t)DD * NN * 2);
    float*  part    = (float*)alloc((size_t)SK * KK * DD * 4);

    float* out_gnew = (float*)d_out;                       // KK*KK
    float* out_newh = out_gnew + (size_t)KK * KK;          // KK*DD
    float* out_idx  = out_newh + (size_t)KK * DD;          // KK

    hipLaunchKernelGGL(k_pre,         dim3(64 + NN), dim3(256),  0, stream, h, g, psum, psq, B);
    hipLaunchKernelGGL(k_stats_final, dim3(1),       dim3(1024), 0, stream, psum, psq, mu, rstd);
    hipLaunchKernelGGL(k_main,        dim3(1024),    dim3(256),  0, stream, h, mu, rstd, gamma, beta, B, w_proj, b_proj, hn, zpf, T, Z1, Z3, degi);
    hipLaunchKernelGGL(k_scorekeys,   dim3(16),      dim3(256),  0, stream, Z1, Z3, zpf, degi, sigma1, scores, keys);
    hipLaunchKernelGGL(k_rank,        dim3(256),     dim3(256),  0, stream, keys, idx_int, out_idx);
    hipLaunchKernelGGL(k_mid,         dim3(128 + 256), dim3(256), 0, stream, T, idx_int, scores, hn, inv_rs, haT_hi, haT_lo);
    hipLaunchKernelGGL(k_nh,          dim3(256),     dim3(256),  0, stream, T, idx_int, haT_hi, haT_lo, part);
    hipLaunchKernelGGL(k_out,         dim3(KK + 512), dim3(256), 0, stream, T, idx_int, inv_rs, part, out_gnew, out_newh);
}